// Round 10
// baseline (507.664 us; speedup 1.0000x reference)
//
#include <hip/hip_runtime.h>

#define NPRI 21504
#define BATCH 64
#define KTOP 1024
#define NCH 21

typedef unsigned long long u64;
typedef unsigned int u32;

// correctly-rounded f32 exp via f64 libm exp (validated: absmax 3e-8)
__device__ __forceinline__ float crexpf(float x) { return (float)exp((double)x); }

// Key packing: score>0 so f32 bits are order-monotone. NPRI-1-idx < 2^15.
// Descending u64 order == (score desc, idx asc) == lax.top_k stable order.
// Keys are UNIQUE (idx embedded) => top-1024 multiset + desc order is unique,
// so any correct selection structure is bit-exact.

// K1: fused f32-stepwise softmax score + per-chunk bitonic sort (desc) of u64 keys.
__global__ __launch_bounds__(256) void k_sort(const float* __restrict__ confs,
                                              u64* __restrict__ keyG) {
  const int b = blockIdx.x / NCH;
  const int c = blockIdx.x % NCH;
  __shared__ u64 ks[KTOP];
  const float2* cf = (const float2*)confs + (size_t)b * NPRI + c * KTOP;
  for (int i = threadIdx.x; i < KTOP; i += 256) {
    float2 v = cf[i];
    float m = fmaxf(v.x, v.y);
    float e0 = crexpf(v.x - m);
    float e1 = crexpf(v.y - m);
    float s = e1 / (e0 + e1);          // exact f32 steps (validated)
    int idx = c * KTOP + i;
    ks[i] = ((u64)__float_as_uint(s) << 15) | (u64)(NPRI - 1 - idx);
  }
  for (int k = 2; k <= KTOP; k <<= 1) {
    for (int j = k >> 1; j > 0; j >>= 1) {
      __syncthreads();
      for (int l = threadIdx.x; l < KTOP; l += 256) {
        int p = l ^ j;
        if (p > l) {
          u64 a = ks[l], q = ks[p];
          bool up = ((l & k) == 0);
          if ((a > q) != up) { ks[l] = q; ks[p] = a; }
        }
      }
    }
  }
  __syncthreads();
  u64* dst = keyG + (size_t)b * NPRI + (size_t)c * KTOP;
  for (int i = threadIdx.x; i < KTOP; i += 256) dst[i] = ks[i];
}

// K2 (xN levels): pairwise top-1024 merge of sorted runs. When nIn is odd, the
// last run is copied. finalDecode=1 on the last level: decode + valid-ballot.
__global__ __launch_bounds__(256) void k_mergeL(const u64* __restrict__ src,
                                                u64* __restrict__ dst, int nIn,
                                                const float* __restrict__ locs,
                                                const float* __restrict__ priors,
                                                float* __restrict__ boxF,
                                                float* __restrict__ scoreF,
                                                u64* __restrict__ validW,
                                                int finalDecode) {
  const int nOut = (nIn + 1) >> 1;
  const int b = blockIdx.x / nOut;
  const int m = blockIdx.x % nOut;
  const u64* sA = src + ((size_t)b * nIn + 2 * m) * KTOP;
  u64* d = dst + ((size_t)b * nOut + m) * KTOP;
  __shared__ u64 A[KTOP];
  if (2 * m + 1 < nIn) {
    const u64* sB = sA + KTOP;
    // half-cleaner: A[i] vs reversed B -> elementwise max = bitonic top-1024
    for (int i = threadIdx.x; i < KTOP; i += 256) {
      u64 a = sA[i];
      u64 q = sB[KTOP - 1 - i];
      A[i] = a > q ? a : q;
    }
    // clean -> descending
    for (int j = KTOP / 2; j > 0; j >>= 1) {
      __syncthreads();
      for (int l = threadIdx.x; l < KTOP; l += 256) {
        int p = l ^ j;
        if (p > l) {
          u64 a = A[l], q = A[p];
          if (a < q) { A[l] = q; A[p] = a; }
        }
      }
    }
    __syncthreads();
    if (!finalDecode)
      for (int i = threadIdx.x; i < KTOP; i += 256) d[i] = A[i];
  } else {
    for (int i = threadIdx.x; i < KTOP; i += 256) d[i] = sA[i];
  }
  if (finalDecode) {
    // f32-stepwise decode (identical expressions to validated round 7)
    for (int i = threadIdx.x; i < KTOP; i += 256) {
      u64 K = A[i];
      float sv = __uint_as_float((u32)(K >> 15));
      int idx = NPRI - 1 - (int)(K & 0x7FFFu);
      float4 lo = ((const float4*)locs)[(size_t)b * NPRI + idx];
      float4 pr = ((const float4*)priors)[idx];
      float cx = pr.x + (lo.x * 0.1f) * pr.z;
      float cy = pr.y + (lo.y * 0.1f) * pr.w;
      float w  = pr.z * crexpf(lo.z * 0.2f);
      float h  = pr.w * crexpf(lo.w * 0.2f);
      float x1 = cx - w * 0.5f;
      float y1 = cy - h * 0.5f;
      float x2 = x1 + w;
      float y2 = y1 + h;
      size_t o = (size_t)b * KTOP + i;
      boxF[o * 4 + 0] = x1;
      boxF[o * 4 + 1] = y1;
      boxF[o * 4 + 2] = x2;
      boxF[o * 4 + 3] = y2;
      scoreF[o] = sv;
      u64 mask = __ballot(sv > 0.5f);       // wave covers group i>>6
      if ((threadIdx.x & 63) == 0) validW[(size_t)b * 16 + (i >> 6)] = mask;
    }
  }
}

// K3: upper-triangle suppression bitmask. Block (g,b) owns rows [g*64,g*64+64)
// and computes only words w in [g,16): bit j of (i,w) = iou(i,j)>0.4f && j>i.
// Words w<g are never written NOR read (k_scan only touches w>=g). Bit-exact
// vs full version on every word that is read.
__global__ __launch_bounds__(256) void k_iou(const float* __restrict__ boxF,
                                             u64* __restrict__ sup) {
  const int b = blockIdx.y;
  const int g = blockIdx.x;            // row group 0..15
  const int nw = 16 - g;               // words per row
  __shared__ float X1[KTOP], Y1[KTOP], X2[KTOP], Y2[KTOP], AR[KTOP];
  const float* bb = boxF + (size_t)b * KTOP * 4;
  for (int l = g * 64 + threadIdx.x; l < KTOP; l += 256) {
    float x1 = bb[l * 4 + 0], y1 = bb[l * 4 + 1];
    float x2 = bb[l * 4 + 2], y2 = bb[l * 4 + 3];
    X1[l] = x1; Y1[l] = y1; X2[l] = x2; Y2[l] = y2;
    AR[l] = fmaxf(x2 - x1, 0.0f) * fmaxf(y2 - y1, 0.0f);
  }
  __syncthreads();
  const int ntask = 64 * nw;           // (row, word) pairs
  for (int T = threadIdx.x; T < ntask; T += 256) {
    int r = T / nw;
    int w = g + (T - r * nw);
    int i = g * 64 + r;
    float x1 = X1[i], y1 = Y1[i], x2 = X2[i], y2 = Y2[i], a = AR[i];
    u64 word = 0;
    const int jbase = w * 64;
    for (int jb = 0; jb < 64; jb++) {
      int j = jbase + jb;
      float lx = fmaxf(x1, X1[j]);
      float ly = fmaxf(y1, Y1[j]);
      float rx = fminf(x2, X2[j]);
      float ry = fminf(y2, Y2[j]);
      float iw = fmaxf(rx - lx, 0.0f);
      float ih = fmaxf(ry - ly, 0.0f);
      float inter = iw * ih;
      float uni = (a + AR[j]) - inter;
      float iou = inter / fmaxf(uni, 1e-9f);
      if (iou > 0.4f) word |= (1ULL << jb);
    }
    if (w == g) word &= (r == 63) ? 0ULL : (~0ULL << (r + 1));   // j > i
    sup[((size_t)b * KTOP + i) * 16 + w] = word;
  }
}

// K4: group-synchronous greedy NMS (validated round 9). Per 64-group: wave-0
// serial alive-mask recurrence, then all 256 threads OR kept rows into future
// removal words. Exact greedy semantics.
__global__ __launch_bounds__(256) void k_scan(const u64* __restrict__ sup,
                                              const u64* __restrict__ validW,
                                              const float* __restrict__ boxF,
                                              const float* __restrict__ scoreF,
                                              float* __restrict__ out) {
  const int b = blockIdx.x;
  const int t = threadIdx.x;
  __shared__ u64 rows[64][16];
  __shared__ u64 remv[16];
  __shared__ u64 keepW[16];
  __shared__ u64 vW[16];
  if (t < 16) { remv[t] = 0; vW[t] = validW[(size_t)b * 16 + t]; }
  __syncthreads();
  for (int g = 0; g < 16; g++) {
    for (int l = t; l < 1024; l += 256)
      rows[l >> 4][l & 15] = sup[((size_t)b * KTOP + g * 64) * 16 + l];
    __syncthreads();
    if (t < 64) {
      u64 diag = rows[t][g];                // lane i: row i's intra-group word
      u64 alive = vW[g] & ~remv[g];         // wave-uniform
      for (int i = 0; i < 64; i++) {
        if ((alive >> i) & 1ULL)            // uniform -> scalar branch
          alive &= ~__shfl(diag, i);        // row i only has bits j>i
      }
      if (t == 0) keepW[g] = alive;
    }
    __syncthreads();
    {
      u64 kw = keepW[g];
      int w = t & 15;
      if (w > g) {
        int i0 = (t >> 4) * 4;
        u64 acc = 0;
        for (int i = i0; i < i0 + 4; i++)
          if ((kw >> i) & 1ULL) acc |= rows[i][w];
        if (acc) atomicOr(&remv[w], acc);
      }
    }
    __syncthreads();   // remv visible; rows reusable
  }
  const float* bb = boxF + (size_t)b * KTOP * 4;
  const float* sc = scoreF + (size_t)b * KTOP;
  for (int i = t; i < KTOP; i += 256) {
    float kf = ((keepW[i >> 6] >> (i & 63)) & 1ULL) ? 1.0f : 0.0f;
    size_t o5 = ((size_t)b * KTOP + i) * 5;
    out[o5 + 0] = bb[i * 4 + 0] * kf;
    out[o5 + 1] = bb[i * 4 + 1] * kf;
    out[o5 + 2] = bb[i * 4 + 2] * kf;
    out[o5 + 3] = bb[i * 4 + 3] * kf;
    out[o5 + 4] = sc[i] * kf;
    out[(size_t)BATCH * KTOP * 5 + (size_t)b * KTOP + i] = kf;
  }
}

extern "C" void kernel_launch(void* const* d_in, const int* in_sizes, int n_in,
                              void* d_out, int out_size, void* d_ws, size_t ws_size,
                              hipStream_t stream) {
  const float* locs = nullptr;
  const float* confs = nullptr;
  const float* priors = nullptr;
  for (int i = 0; i < n_in; i++) {
    if (in_sizes[i] == BATCH * NPRI * 4) locs = (const float*)d_in[i];
    else if (in_sizes[i] == BATCH * NPRI * 2) confs = (const float*)d_in[i];
    else if (in_sizes[i] == NPRI * 4) priors = (const float*)d_in[i];
  }
  float* out = (float*)d_out;   // f32: [B,K,5] dets ++ [B,K] keep

  char* ws = (char*)d_ws;
  size_t off = 0;
  u64* keyG = (u64*)(ws + off);          // B*N*8 = 11,010,048
  u64* sup = (u64*)(ws + off);           // alias: keyG dead after last merge (8,388,608)
  off += (size_t)BATCH * NPRI * 8;
  u64* bufB = (u64*)(ws + off);          off += (size_t)BATCH * 11 * KTOP * 8;  // 5,767,168
  float* boxF = (float*)(ws + off);      off += (size_t)BATCH * KTOP * 4 * 4;   // 1,048,576
  float* scoreF = (float*)(ws + off);    off += (size_t)BATCH * KTOP * 4;       //   262,144
  u64* validW = (u64*)(ws + off);        off += (size_t)BATCH * 16 * 8;         //     8,192
  // total ~18.1 MB

  k_sort<<<BATCH * NCH, 256, 0, stream>>>(confs, keyG);
  // tree merge: 21 -> 11 -> 6 -> 3 -> 2 -> 1
  k_mergeL<<<BATCH * 11, 256, 0, stream>>>(keyG, bufB, 21, locs, priors, boxF, scoreF, validW, 0);
  k_mergeL<<<BATCH * 6, 256, 0, stream>>>(bufB, keyG, 11, locs, priors, boxF, scoreF, validW, 0);
  k_mergeL<<<BATCH * 3, 256, 0, stream>>>(keyG, bufB, 6, locs, priors, boxF, scoreF, validW, 0);
  k_mergeL<<<BATCH * 2, 256, 0, stream>>>(bufB, keyG, 3, locs, priors, boxF, scoreF, validW, 0);
  k_mergeL<<<BATCH * 1, 256, 0, stream>>>(keyG, bufB, 2, locs, priors, boxF, scoreF, validW, 1);
  k_iou<<<dim3(16, BATCH), 256, 0, stream>>>(boxF, sup);
  k_scan<<<BATCH, 256, 0, stream>>>(sup, validW, boxF, scoreF, out);
}

// Round 11
// 312.001 us; speedup vs baseline: 1.6271x; 1.6271x over previous
//
#include <hip/hip_runtime.h>

#define NPRI 21504
#define BATCH 64
#define KTOP 1024
#define NCH 21

typedef unsigned long long u64;
typedef unsigned int u32;

// correctly-rounded f32 exp via f64 libm exp (validated: absmax 3e-8)
__device__ __forceinline__ float crexpf(float x) { return (float)exp((double)x); }

// Key packing: score>0 so f32 bits are order-monotone. NPRI-1-idx < 2^15.
// Descending u64 order == (score desc, idx asc) == lax.top_k stable order.
// Keys are UNIQUE (idx embedded) => top-1024 multiset + desc order is unique,
// so any correct selection structure is bit-exact.

// K1: fused f32-stepwise softmax score + per-chunk bitonic sort (desc) of u64 keys.
__global__ __launch_bounds__(256) void k_sort(const float* __restrict__ confs,
                                              u64* __restrict__ keyG) {
  const int b = blockIdx.x / NCH;
  const int c = blockIdx.x % NCH;
  __shared__ u64 ks[KTOP];
  const float2* cf = (const float2*)confs + (size_t)b * NPRI + c * KTOP;
  for (int i = threadIdx.x; i < KTOP; i += 256) {
    float2 v = cf[i];
    float m = fmaxf(v.x, v.y);
    float e0 = crexpf(v.x - m);
    float e1 = crexpf(v.y - m);
    float s = e1 / (e0 + e1);          // exact f32 steps (validated)
    int idx = c * KTOP + i;
    ks[i] = ((u64)__float_as_uint(s) << 15) | (u64)(NPRI - 1 - idx);
  }
  for (int k = 2; k <= KTOP; k <<= 1) {
    for (int j = k >> 1; j > 0; j >>= 1) {
      __syncthreads();
      for (int l = threadIdx.x; l < KTOP; l += 256) {
        int p = l ^ j;
        if (p > l) {
          u64 a = ks[l], q = ks[p];
          bool up = ((l & k) == 0);
          if ((a > q) != up) { ks[l] = q; ks[p] = a; }
        }
      }
    }
  }
  __syncthreads();
  u64* dst = keyG + (size_t)b * NPRI + (size_t)c * KTOP;
  for (int i = threadIdx.x; i < KTOP; i += 256) dst[i] = ks[i];
}

// K2 (xN levels): pairwise top-1024 merge of sorted runs. When nIn is odd, the
// last run is copied. finalDecode=1 on the last level: decode + valid-ballot.
__global__ __launch_bounds__(256) void k_mergeL(const u64* __restrict__ src,
                                                u64* __restrict__ dst, int nIn,
                                                const float* __restrict__ locs,
                                                const float* __restrict__ priors,
                                                float* __restrict__ boxF,
                                                float* __restrict__ scoreF,
                                                u64* __restrict__ validW,
                                                int finalDecode) {
  const int nOut = (nIn + 1) >> 1;
  const int b = blockIdx.x / nOut;
  const int m = blockIdx.x % nOut;
  const u64* sA = src + ((size_t)b * nIn + 2 * m) * KTOP;
  u64* d = dst + ((size_t)b * nOut + m) * KTOP;
  __shared__ u64 A[KTOP];
  if (2 * m + 1 < nIn) {
    const u64* sB = sA + KTOP;
    // half-cleaner: A[i] vs reversed B -> elementwise max = bitonic top-1024
    for (int i = threadIdx.x; i < KTOP; i += 256) {
      u64 a = sA[i];
      u64 q = sB[KTOP - 1 - i];
      A[i] = a > q ? a : q;
    }
    // clean -> descending
    for (int j = KTOP / 2; j > 0; j >>= 1) {
      __syncthreads();
      for (int l = threadIdx.x; l < KTOP; l += 256) {
        int p = l ^ j;
        if (p > l) {
          u64 a = A[l], q = A[p];
          if (a < q) { A[l] = q; A[p] = a; }
        }
      }
    }
    __syncthreads();
    if (!finalDecode)
      for (int i = threadIdx.x; i < KTOP; i += 256) d[i] = A[i];
  } else {
    for (int i = threadIdx.x; i < KTOP; i += 256) d[i] = sA[i];
  }
  if (finalDecode) {
    // f32-stepwise decode (identical expressions to validated round 7)
    for (int i = threadIdx.x; i < KTOP; i += 256) {
      u64 K = A[i];
      float sv = __uint_as_float((u32)(K >> 15));
      int idx = NPRI - 1 - (int)(K & 0x7FFFu);
      float4 lo = ((const float4*)locs)[(size_t)b * NPRI + idx];
      float4 pr = ((const float4*)priors)[idx];
      float cx = pr.x + (lo.x * 0.1f) * pr.z;
      float cy = pr.y + (lo.y * 0.1f) * pr.w;
      float w  = pr.z * crexpf(lo.z * 0.2f);
      float h  = pr.w * crexpf(lo.w * 0.2f);
      float x1 = cx - w * 0.5f;
      float y1 = cy - h * 0.5f;
      float x2 = x1 + w;
      float y2 = y1 + h;
      size_t o = (size_t)b * KTOP + i;
      boxF[o * 4 + 0] = x1;
      boxF[o * 4 + 1] = y1;
      boxF[o * 4 + 2] = x2;
      boxF[o * 4 + 3] = y2;
      scoreF[o] = sv;
      u64 mask = __ballot(sv > 0.5f);       // wave covers group i>>6
      if ((threadIdx.x & 63) == 0) validW[(size_t)b * 16 + (i >> 6)] = mask;
    }
  }
}

// K3: upper-triangle suppression bitmask, broadcast-friendly mapping.
// Block (g,b) owns rows [g*64, g*64+64). Thread t: row r = t&63, wave v = t>>6.
// Wave v computes words w = g+v, g+v+4, ... — w is WAVE-UNIFORM, so inner-loop
// LDS reads are same-address broadcasts (conflict-free; round-10's per-lane w
// caused 16-way bank conflicts, 5e7 SQ_LDS_BANK_CONFLICT). Boxes packed float4
// (1 ds_read_b128 + 1 ds_read_b32 per j instead of 5 b32).
// Words w<g are never written nor read (k_scan only touches w>=g).
__global__ __launch_bounds__(256) void k_iou(const float* __restrict__ boxF,
                                             u64* __restrict__ sup) {
  const int b = blockIdx.y;
  const int g = blockIdx.x;            // row group 0..15
  __shared__ float4 BXS[KTOP];
  __shared__ float ARS[KTOP];
  const float4* bb = (const float4*)(boxF + (size_t)b * KTOP * 4);
  for (int l = g * 64 + threadIdx.x; l < KTOP; l += 256) {
    float4 v = bb[l];
    BXS[l] = v;
    ARS[l] = fmaxf(v.z - v.x, 0.0f) * fmaxf(v.w - v.y, 0.0f);
  }
  __syncthreads();
  const int r = threadIdx.x & 63;
  const int v = threadIdx.x >> 6;      // wave 0..3
  const int i = g * 64 + r;
  const float4 bi = BXS[i];
  const float a = ARS[i];
  for (int w = g + v; w < 16; w += 4) {
    u64 word = 0;
    const int jbase = w * 64;
    for (int jb = 0; jb < 64; jb++) {
      int j = jbase + jb;
      float4 bj = BXS[j];              // broadcast (w uniform in wave)
      float aj = ARS[j];
      float lx = fmaxf(bi.x, bj.x);
      float ly = fmaxf(bi.y, bj.y);
      float rx = fminf(bi.z, bj.z);
      float ry = fminf(bi.w, bj.w);
      float iw = fmaxf(rx - lx, 0.0f);
      float ih = fmaxf(ry - ly, 0.0f);
      float inter = iw * ih;
      float uni = (a + aj) - inter;
      float iou = inter / fmaxf(uni, 1e-9f);
      if (iou > 0.4f) word |= (1ULL << jb);
    }
    if (w == g) word &= (r == 63) ? 0ULL : (~0ULL << (r + 1));   // j > i
    sup[((size_t)b * KTOP + i) * 16 + w] = word;
  }
}

// K4: group-synchronous greedy NMS (validated round 9). Per 64-group: wave-0
// serial alive-mask recurrence, then all 256 threads OR kept rows into future
// removal words. Exact greedy semantics.
__global__ __launch_bounds__(256) void k_scan(const u64* __restrict__ sup,
                                              const u64* __restrict__ validW,
                                              const float* __restrict__ boxF,
                                              const float* __restrict__ scoreF,
                                              float* __restrict__ out) {
  const int b = blockIdx.x;
  const int t = threadIdx.x;
  __shared__ u64 rows[64][16];
  __shared__ u64 remv[16];
  __shared__ u64 keepW[16];
  __shared__ u64 vW[16];
  if (t < 16) { remv[t] = 0; vW[t] = validW[(size_t)b * 16 + t]; }
  __syncthreads();
  for (int g = 0; g < 16; g++) {
    for (int l = t; l < 1024; l += 256)
      rows[l >> 4][l & 15] = sup[((size_t)b * KTOP + g * 64) * 16 + l];
    __syncthreads();
    if (t < 64) {
      u64 diag = rows[t][g];                // lane i: row i's intra-group word
      u64 alive = vW[g] & ~remv[g];         // wave-uniform
      for (int i = 0; i < 64; i++) {
        if ((alive >> i) & 1ULL)            // uniform -> scalar branch
          alive &= ~__shfl(diag, i);        // row i only has bits j>i
      }
      if (t == 0) keepW[g] = alive;
    }
    __syncthreads();
    {
      u64 kw = keepW[g];
      int w = t & 15;
      if (w > g) {
        int i0 = (t >> 4) * 4;
        u64 acc = 0;
        for (int i = i0; i < i0 + 4; i++)
          if ((kw >> i) & 1ULL) acc |= rows[i][w];
        if (acc) atomicOr(&remv[w], acc);
      }
    }
    __syncthreads();   // remv visible; rows reusable
  }
  const float* bb = boxF + (size_t)b * KTOP * 4;
  const float* sc = scoreF + (size_t)b * KTOP;
  for (int i = t; i < KTOP; i += 256) {
    float kf = ((keepW[i >> 6] >> (i & 63)) & 1ULL) ? 1.0f : 0.0f;
    size_t o5 = ((size_t)b * KTOP + i) * 5;
    out[o5 + 0] = bb[i * 4 + 0] * kf;
    out[o5 + 1] = bb[i * 4 + 1] * kf;
    out[o5 + 2] = bb[i * 4 + 2] * kf;
    out[o5 + 3] = bb[i * 4 + 3] * kf;
    out[o5 + 4] = sc[i] * kf;
    out[(size_t)BATCH * KTOP * 5 + (size_t)b * KTOP + i] = kf;
  }
}

extern "C" void kernel_launch(void* const* d_in, const int* in_sizes, int n_in,
                              void* d_out, int out_size, void* d_ws, size_t ws_size,
                              hipStream_t stream) {
  const float* locs = nullptr;
  const float* confs = nullptr;
  const float* priors = nullptr;
  for (int i = 0; i < n_in; i++) {
    if (in_sizes[i] == BATCH * NPRI * 4) locs = (const float*)d_in[i];
    else if (in_sizes[i] == BATCH * NPRI * 2) confs = (const float*)d_in[i];
    else if (in_sizes[i] == NPRI * 4) priors = (const float*)d_in[i];
  }
  float* out = (float*)d_out;   // f32: [B,K,5] dets ++ [B,K] keep

  char* ws = (char*)d_ws;
  size_t off = 0;
  u64* keyG = (u64*)(ws + off);          // B*N*8 = 11,010,048
  u64* sup = (u64*)(ws + off);           // alias: keyG dead after last merge (8,388,608)
  off += (size_t)BATCH * NPRI * 8;
  u64* bufB = (u64*)(ws + off);          off += (size_t)BATCH * 11 * KTOP * 8;  // 5,767,168
  float* boxF = (float*)(ws + off);      off += (size_t)BATCH * KTOP * 4 * 4;   // 1,048,576
  float* scoreF = (float*)(ws + off);    off += (size_t)BATCH * KTOP * 4;       //   262,144
  u64* validW = (u64*)(ws + off);        off += (size_t)BATCH * 16 * 8;         //     8,192
  // total ~18.1 MB

  k_sort<<<BATCH * NCH, 256, 0, stream>>>(confs, keyG);
  // tree merge: 21 -> 11 -> 6 -> 3 -> 2 -> 1
  k_mergeL<<<BATCH * 11, 256, 0, stream>>>(keyG, bufB, 21, locs, priors, boxF, scoreF, validW, 0);
  k_mergeL<<<BATCH * 6, 256, 0, stream>>>(bufB, keyG, 11, locs, priors, boxF, scoreF, validW, 0);
  k_mergeL<<<BATCH * 3, 256, 0, stream>>>(keyG, bufB, 6, locs, priors, boxF, scoreF, validW, 0);
  k_mergeL<<<BATCH * 2, 256, 0, stream>>>(bufB, keyG, 3, locs, priors, boxF, scoreF, validW, 0);
  k_mergeL<<<BATCH * 1, 256, 0, stream>>>(keyG, bufB, 2, locs, priors, boxF, scoreF, validW, 1);
  k_iou<<<dim3(16, BATCH), 256, 0, stream>>>(boxF, sup);
  k_scan<<<BATCH, 256, 0, stream>>>(sup, validW, boxF, scoreF, out);
}

// Round 12
// 281.276 us; speedup vs baseline: 1.8049x; 1.1092x over previous
//
#include <hip/hip_runtime.h>

#define NPRI 21504
#define BATCH 64
#define KTOP 1024
#define NCH 21

typedef unsigned long long u64;
typedef unsigned int u32;

// correctly-rounded f32 exp via f64 libm exp (validated: absmax 3e-8)
__device__ __forceinline__ float crexpf(float x) { return (float)exp((double)x); }

__device__ __forceinline__ u64 readlane64(u64 v, int lane) {
  int lo = __builtin_amdgcn_readlane((int)(u32)v, lane);
  int hi = __builtin_amdgcn_readlane((int)(u32)(v >> 32), lane);
  return ((u64)(u32)hi << 32) | (u64)(u32)lo;
}

// Key packing: score>0 so f32 bits are order-monotone. NPRI-1-idx < 2^15.
// Descending u64 order == (score desc, idx asc) == lax.top_k stable order.
// Keys are UNIQUE (idx embedded) => top-1024 multiset + desc order is unique,
// so any correct selection structure is bit-exact.

// K1: fused f32-stepwise softmax score + per-chunk bitonic sort (desc) of u64 keys.
__global__ __launch_bounds__(256) void k_sort(const float* __restrict__ confs,
                                              u64* __restrict__ keyG) {
  const int b = blockIdx.x / NCH;
  const int c = blockIdx.x % NCH;
  __shared__ u64 ks[KTOP];
  const float2* cf = (const float2*)confs + (size_t)b * NPRI + c * KTOP;
  for (int i = threadIdx.x; i < KTOP; i += 256) {
    float2 v = cf[i];
    float m = fmaxf(v.x, v.y);
    float e0 = crexpf(v.x - m);
    float e1 = crexpf(v.y - m);
    float s = e1 / (e0 + e1);          // exact f32 steps (validated)
    int idx = c * KTOP + i;
    ks[i] = ((u64)__float_as_uint(s) << 15) | (u64)(NPRI - 1 - idx);
  }
  for (int k = 2; k <= KTOP; k <<= 1) {
    for (int j = k >> 1; j > 0; j >>= 1) {
      __syncthreads();
      for (int l = threadIdx.x; l < KTOP; l += 256) {
        int p = l ^ j;
        if (p > l) {
          u64 a = ks[l], q = ks[p];
          bool up = ((l & k) == 0);
          if ((a > q) != up) { ks[l] = q; ks[p] = a; }
        }
      }
    }
  }
  __syncthreads();
  u64* dst = keyG + (size_t)b * NPRI + (size_t)c * KTOP;
  for (int i = threadIdx.x; i < KTOP; i += 256) dst[i] = ks[i];
}

// K2 (xN levels): pairwise top-1024 merge of sorted runs. When nIn is odd, the
// last run is copied. finalDecode=1 on the last level: decode + valid-ballot.
__global__ __launch_bounds__(256) void k_mergeL(const u64* __restrict__ src,
                                                u64* __restrict__ dst, int nIn,
                                                const float* __restrict__ locs,
                                                const float* __restrict__ priors,
                                                float* __restrict__ boxF,
                                                float* __restrict__ scoreF,
                                                u64* __restrict__ validW,
                                                int finalDecode) {
  const int nOut = (nIn + 1) >> 1;
  const int b = blockIdx.x / nOut;
  const int m = blockIdx.x % nOut;
  const u64* sA = src + ((size_t)b * nIn + 2 * m) * KTOP;
  u64* d = dst + ((size_t)b * nOut + m) * KTOP;
  __shared__ u64 A[KTOP];
  if (2 * m + 1 < nIn) {
    const u64* sB = sA + KTOP;
    // half-cleaner: A[i] vs reversed B -> elementwise max = bitonic top-1024
    for (int i = threadIdx.x; i < KTOP; i += 256) {
      u64 a = sA[i];
      u64 q = sB[KTOP - 1 - i];
      A[i] = a > q ? a : q;
    }
    // clean -> descending
    for (int j = KTOP / 2; j > 0; j >>= 1) {
      __syncthreads();
      for (int l = threadIdx.x; l < KTOP; l += 256) {
        int p = l ^ j;
        if (p > l) {
          u64 a = A[l], q = A[p];
          if (a < q) { A[l] = q; A[p] = a; }
        }
      }
    }
    __syncthreads();
    if (!finalDecode)
      for (int i = threadIdx.x; i < KTOP; i += 256) d[i] = A[i];
  } else {
    for (int i = threadIdx.x; i < KTOP; i += 256) d[i] = sA[i];
  }
  if (finalDecode) {
    // f32-stepwise decode (identical expressions to validated round 7)
    for (int i = threadIdx.x; i < KTOP; i += 256) {
      u64 K = A[i];
      float sv = __uint_as_float((u32)(K >> 15));
      int idx = NPRI - 1 - (int)(K & 0x7FFFu);
      float4 lo = ((const float4*)locs)[(size_t)b * NPRI + idx];
      float4 pr = ((const float4*)priors)[idx];
      float cx = pr.x + (lo.x * 0.1f) * pr.z;
      float cy = pr.y + (lo.y * 0.1f) * pr.w;
      float w  = pr.z * crexpf(lo.z * 0.2f);
      float h  = pr.w * crexpf(lo.w * 0.2f);
      float x1 = cx - w * 0.5f;
      float y1 = cy - h * 0.5f;
      float x2 = x1 + w;
      float y2 = y1 + h;
      size_t o = (size_t)b * KTOP + i;
      boxF[o * 4 + 0] = x1;
      boxF[o * 4 + 1] = y1;
      boxF[o * 4 + 2] = x2;
      boxF[o * 4 + 3] = y2;
      scoreF[o] = sv;
      u64 mask = __ballot(sv > 0.5f);       // wave covers group i>>6
      if ((threadIdx.x & 63) == 0) validW[(size_t)b * 16 + (i >> 6)] = mask;
    }
  }
}

// K3: upper-triangle suppression bitmask, broadcast-friendly mapping
// (validated round 11: wave-uniform word index => conflict-free broadcasts).
__global__ __launch_bounds__(256) void k_iou(const float* __restrict__ boxF,
                                             u64* __restrict__ sup) {
  const int b = blockIdx.y;
  const int g = blockIdx.x;            // row group 0..15
  __shared__ float4 BXS[KTOP];
  __shared__ float ARS[KTOP];
  const float4* bb = (const float4*)(boxF + (size_t)b * KTOP * 4);
  for (int l = g * 64 + threadIdx.x; l < KTOP; l += 256) {
    float4 v = bb[l];
    BXS[l] = v;
    ARS[l] = fmaxf(v.z - v.x, 0.0f) * fmaxf(v.w - v.y, 0.0f);
  }
  __syncthreads();
  const int r = threadIdx.x & 63;
  const int v = threadIdx.x >> 6;      // wave 0..3
  const int i = g * 64 + r;
  const float4 bi = BXS[i];
  const float a = ARS[i];
  for (int w = g + v; w < 16; w += 4) {
    u64 word = 0;
    const int jbase = w * 64;
    for (int jb = 0; jb < 64; jb++) {
      int j = jbase + jb;
      float4 bj = BXS[j];              // broadcast (w uniform in wave)
      float aj = ARS[j];
      float lx = fmaxf(bi.x, bj.x);
      float ly = fmaxf(bi.y, bj.y);
      float rx = fminf(bi.z, bj.z);
      float ry = fminf(bi.w, bj.w);
      float iw = fmaxf(rx - lx, 0.0f);
      float ih = fmaxf(ry - ly, 0.0f);
      float inter = iw * ih;
      float uni = (a + aj) - inter;
      float iou = inter / fmaxf(uni, 1e-9f);
      if (iou > 0.4f) word |= (1ULL << jb);
    }
    if (w == g) word &= (r == 63) ? 0ULL : (~0ULL << (r + 1));   // j > i
    sup[((size_t)b * KTOP + i) * 16 + w] = word;
  }
}

// K4: group-synchronous greedy NMS v2. Per 64-group:
//  - chain: pop only KEPT bits via ctz + v_readlane (uniform index, ~8cy) —
//    replaces 64 dependent ds_bpermute shuffles;
//  - next group's 8KB rows prefetched into registers before the barrier wave-0
//    hides behind (double-buffered LDS) — global latency off the serial path.
// Greedy semantics identical: ascending-index processing, suppressed rows never
// suppress others (kept-only popping is equivalent).
__global__ __launch_bounds__(256) void k_scan(const u64* __restrict__ sup,
                                              const u64* __restrict__ validW,
                                              const float* __restrict__ boxF,
                                              const float* __restrict__ scoreF,
                                              float* __restrict__ out) {
  const int b = blockIdx.x;
  const int t = threadIdx.x;
  __shared__ u64 rows[2][64][16];      // 16 KB double buffer
  __shared__ u64 remv[16];
  __shared__ u64 keepW[16];
  __shared__ u64 vW[16];
  const u64* supB = sup + (size_t)b * KTOP * 16;
  // preload group 0
  for (int l = t; l < 1024; l += 256)
    rows[0][l >> 4][l & 15] = supB[l];
  if (t < 16) { remv[t] = 0; vW[t] = validW[(size_t)b * 16 + t]; }
  __syncthreads();
  for (int g = 0; g < 16; g++) {
    const int cur = g & 1;
    // issue prefetch of group g+1 into registers (latency overlaps wave-0 chain)
    u64 pf0, pf1, pf2, pf3;
    if (g < 15) {
      const u64* nsrc = supB + (size_t)(g + 1) * 1024;
      pf0 = nsrc[t];
      pf1 = nsrc[t + 256];
      pf2 = nsrc[t + 512];
      pf3 = nsrc[t + 768];
    }
    if (t < 64) {
      u64 diag = rows[cur][t][g];        // lane i: row i's intra-group word
      u64 alive = vW[g] & ~remv[g];      // wave-uniform
      u64 keep = 0;
      u64 m = alive;
      while (m) {
        int i = __builtin_ctzll(m);
        keep |= (1ULL << i);
        u64 row = readlane64(diag, i);   // row i has only bits j>i
        alive &= ~row;
        m = (i == 63) ? 0ULL : (alive & (~0ULL << (i + 1)));
      }
      if (t == 0) keepW[g] = keep;
    }
    __syncthreads();
    // OR kept rows into removal words of future groups
    {
      u64 kw = keepW[g];
      int w = t & 15;
      if (w > g) {
        int i0 = (t >> 4) * 4;
        u64 acc = 0;
        for (int i = i0; i < i0 + 4; i++)
          if ((kw >> i) & 1ULL) acc |= rows[cur][i][w];
        if (acc) atomicOr(&remv[w], acc);
      }
    }
    // store prefetched rows into the other buffer
    if (g < 15) {
      u64* dstb = &rows[cur ^ 1][0][0];
      dstb[t] = pf0;
      dstb[t + 256] = pf1;
      dstb[t + 512] = pf2;
      dstb[t + 768] = pf3;
    }
    __syncthreads();   // remv + next buffer visible
  }
  const float* bb = boxF + (size_t)b * KTOP * 4;
  const float* sc = scoreF + (size_t)b * KTOP;
  for (int i = t; i < KTOP; i += 256) {
    float kf = ((keepW[i >> 6] >> (i & 63)) & 1ULL) ? 1.0f : 0.0f;
    size_t o5 = ((size_t)b * KTOP + i) * 5;
    out[o5 + 0] = bb[i * 4 + 0] * kf;
    out[o5 + 1] = bb[i * 4 + 1] * kf;
    out[o5 + 2] = bb[i * 4 + 2] * kf;
    out[o5 + 3] = bb[i * 4 + 3] * kf;
    out[o5 + 4] = sc[i] * kf;
    out[(size_t)BATCH * KTOP * 5 + (size_t)b * KTOP + i] = kf;
  }
}

extern "C" void kernel_launch(void* const* d_in, const int* in_sizes, int n_in,
                              void* d_out, int out_size, void* d_ws, size_t ws_size,
                              hipStream_t stream) {
  const float* locs = nullptr;
  const float* confs = nullptr;
  const float* priors = nullptr;
  for (int i = 0; i < n_in; i++) {
    if (in_sizes[i] == BATCH * NPRI * 4) locs = (const float*)d_in[i];
    else if (in_sizes[i] == BATCH * NPRI * 2) confs = (const float*)d_in[i];
    else if (in_sizes[i] == NPRI * 4) priors = (const float*)d_in[i];
  }
  float* out = (float*)d_out;   // f32: [B,K,5] dets ++ [B,K] keep

  char* ws = (char*)d_ws;
  size_t off = 0;
  u64* keyG = (u64*)(ws + off);          // B*N*8 = 11,010,048
  u64* sup = (u64*)(ws + off);           // alias: keyG dead after last merge (8,388,608)
  off += (size_t)BATCH * NPRI * 8;
  u64* bufB = (u64*)(ws + off);          off += (size_t)BATCH * 11 * KTOP * 8;  // 5,767,168
  float* boxF = (float*)(ws + off);      off += (size_t)BATCH * KTOP * 4 * 4;   // 1,048,576
  float* scoreF = (float*)(ws + off);    off += (size_t)BATCH * KTOP * 4;       //   262,144
  u64* validW = (u64*)(ws + off);        off += (size_t)BATCH * 16 * 8;         //     8,192
  // total ~18.1 MB

  k_sort<<<BATCH * NCH, 256, 0, stream>>>(confs, keyG);
  // tree merge: 21 -> 11 -> 6 -> 3 -> 2 -> 1
  k_mergeL<<<BATCH * 11, 256, 0, stream>>>(keyG, bufB, 21, locs, priors, boxF, scoreF, validW, 0);
  k_mergeL<<<BATCH * 6, 256, 0, stream>>>(bufB, keyG, 11, locs, priors, boxF, scoreF, validW, 0);
  k_mergeL<<<BATCH * 3, 256, 0, stream>>>(keyG, bufB, 6, locs, priors, boxF, scoreF, validW, 0);
  k_mergeL<<<BATCH * 2, 256, 0, stream>>>(bufB, keyG, 3, locs, priors, boxF, scoreF, validW, 0);
  k_mergeL<<<BATCH * 1, 256, 0, stream>>>(keyG, bufB, 2, locs, priors, boxF, scoreF, validW, 1);
  k_iou<<<dim3(16, BATCH), 256, 0, stream>>>(boxF, sup);
  k_scan<<<BATCH, 256, 0, stream>>>(sup, validW, boxF, scoreF, out);
}